// Round 1
// baseline (250.491 us; speedup 1.0000x reference)
//
#include <hip/hip_runtime.h>
#include <hip/hip_bf16.h>

typedef __bf16 bf16_t;
typedef __bf16 bf16x8 __attribute__((ext_vector_type(8)));
typedef float f32x4 __attribute__((ext_vector_type(4)));

// async global->LDS, 16B per lane, dest = wave-uniform base + lane*16
#define GLL16(gp, lp)                                                          \
    __builtin_amdgcn_global_load_lds(                                          \
        (const __attribute__((address_space(1))) void*)(gp),                   \
        (__attribute__((address_space(3))) void*)(lp), 16, 0, 0)

// ---------------- E8 lattice quantization (fp64 decisions) ----------------

__device__ __forceinline__ void nearest_D8_d(const double x[8], double f[8]) {
    double d[8];
    double fs = 0.0;
#pragma unroll
    for (int i = 0; i < 8; ++i) {
        f[i] = rint(x[i]);              // round-half-to-even == jnp.round
        d[i] = x[i] - f[i];
        fs += f[i];                     // exact (small integers)
    }
    long long s = (long long)fs;
    if (s & 1LL) {                      // odd parity: flip coord w/ max |d|
        int idx = 0;
        double best = fabs(d[0]);
#pragma unroll
        for (int i = 1; i < 8; ++i) {
            double a = fabs(d[i]);
            if (a > best) { best = a; idx = i; }   // strict > : first max
        }
        f[idx] += (d[idx] >= 0.0) ? 1.0 : -1.0;    // -0.0 >= 0 -> +1, matches
    }
}

__device__ __forceinline__ void e8_quantize_d(const double x[8], float q[8]) {
    double y0[8], y1[8], xs[8];
    nearest_D8_d(x, y0);
#pragma unroll
    for (int i = 0; i < 8; ++i) xs[i] = x[i] - 0.5;
    nearest_D8_d(xs, y1);
#pragma unroll
    for (int i = 0; i < 8; ++i) y1[i] += 0.5;
    double d0 = 0.0, d1 = 0.0;
#pragma unroll
    for (int i = 0; i < 8; ++i) {
        double a = x[i] - y0[i]; d0 += a * a;
        double b = x[i] - y1[i]; d1 += b * b;
    }
    bool take0 = (d0 <= d1);
#pragma unroll
    for (int i = 0; i < 8; ++i) q[i] = (float)(take0 ? y0[i] : y1[i]);
}

// one block per weight row: fp64 row norm -> E8 quantize -> bf16 Q + f32 scale
__global__ __launch_bounds__(256) void quant_kernel(
    const float* __restrict__ W, bf16_t* __restrict__ Q,
    float* __restrict__ scale, int IN, double sfd)
{
    const int row  = blockIdx.x;
    const int t    = threadIdx.x;
    const int lane = t & 63, w = t >> 6;
    const float* wrow = W + (size_t)row * IN;

    // ---- sum of squares in fp64 (float squares are exact in fp64) ----
    double ss = 0.0;
    for (int i = t; i < (IN >> 2); i += 256) {
        float4 v = *(const float4*)(wrow + i * 4);
        double a = v.x, b = v.y, c = v.z, d = v.w;
        ss += a * a + b * b + c * c + d * d;
    }
#pragma unroll
    for (int m = 1; m < 64; m <<= 1) ss += __shfl_xor(ss, m);
    __shared__ double red[4];
    if (lane == 0) red[w] = ss;
    __syncthreads();
    double S   = (red[0] + red[1]) + (red[2] + red[3]);
    double nsd = fmax(sqrt(S), 1e-8);

    // ---- quantize 8-element blocks ----
    for (int b = t; b < (IN >> 3); b += 256) {
        const float* xp = wrow + b * 8;
        float4 v0 = *(const float4*)xp;
        float4 v1 = *(const float4*)(xp + 4);
        double xd[8] = {v0.x, v0.y, v0.z, v0.w, v1.x, v1.y, v1.z, v1.w};
        double xsd[8];
#pragma unroll
        for (int i = 0; i < 8; ++i) xsd[i] = (xd[i] / nsd) * sfd;
        float qf[8];
        e8_quantize_d(xsd, qf);
        bf16x8 o;
#pragma unroll
        for (int i = 0; i < 8; ++i) o[i] = (bf16_t)qf[i];  // exact: half-ints
        *(bf16x8*)(Q + (size_t)row * IN + b * 8) = o;
    }
    if (t == 0) scale[row] = (float)(nsd / sfd);
}

// ---------------- x: f32 -> bf16, vectorized ----------------

__global__ void cvt_kernel(const float* __restrict__ x, bf16_t* __restrict__ y,
                           long long n8)
{
    long long i = (long long)blockIdx.x * blockDim.x + threadIdx.x;
    long long stride = (long long)gridDim.x * blockDim.x;
    for (; i < n8; i += stride) {
        float4 v0 = *(const float4*)(x + i * 8);
        float4 v1 = *(const float4*)(x + i * 8 + 4);
        bf16x8 o;
        o[0] = (bf16_t)v0.x; o[1] = (bf16_t)v0.y;
        o[2] = (bf16_t)v0.z; o[3] = (bf16_t)v0.w;
        o[4] = (bf16_t)v1.x; o[5] = (bf16_t)v1.y;
        o[6] = (bf16_t)v1.z; o[7] = (bf16_t)v1.w;
        *(bf16x8*)(y + i * 8) = o;
    }
}

// ---------------- GEMM: C[m,n] = (sum_k A[m,k]*B[n,k]) * scale[n] + bias[n]
// m97 structure: 128x128 tile, BK=32, 4 waves (2x2), 16x16x32 bf16 MFMA,
// global_load_lds width=16, 2 barriers per K-step.

#define BM 128
#define BN 128
#define BK 32

__global__ __launch_bounds__(256) void gemm_kernel(
    const bf16_t* __restrict__ A,      // [M][K]
    const bf16_t* __restrict__ B,      // [N][K]
    const float* __restrict__ scale,   // [N]
    const float* __restrict__ bias,    // [N]
    float* __restrict__ C,             // [M][N]
    int M, int N, int K)
{
    __shared__ __align__(16) bf16_t lds_a[BM * BK];
    __shared__ __align__(16) bf16_t lds_b[BN * BK];

    const int t    = threadIdx.x;
    const int lane = t & 63;
    const int w    = t >> 6;
    const int wr   = w >> 1, wc = w & 1;       // 2x2 waves, each 64x64 out
    const int fr   = lane & 15;                // fragment row/col
    const int fk   = (lane >> 4) << 3;         // k offset (8 contiguous)

    const int by = blockIdx.y, bx = blockIdx.x;

    // staging: thread tt stages 16B; row = tt>>2, col8 = (tt&3)*8; 2 chunks
    const bf16_t* ga0 = A + (size_t)(by * BM + (t >> 2)) * K + (t & 3) * 8;
    const bf16_t* ga1 = ga0 + (size_t)64 * K;
    const bf16_t* gb0 = B + (size_t)(bx * BN + (t >> 2)) * K + (t & 3) * 8;
    const bf16_t* gb1 = gb0 + (size_t)64 * K;

    f32x4 acc[4][4];
    const f32x4 zero = {0.f, 0.f, 0.f, 0.f};
#pragma unroll
    for (int m = 0; m < 4; ++m)
#pragma unroll
        for (int n = 0; n < 4; ++n) acc[m][n] = zero;

    const bf16_t* pa = &lds_a[(wr * 64 + fr) * BK + fk];
    const bf16_t* pb = &lds_b[(wc * 64 + fr) * BK + fk];

    for (int k0 = 0; k0 < K; k0 += BK) {
        __syncthreads();
        GLL16(ga0 + k0, &lds_a[t * 8]);
        GLL16(ga1 + k0, &lds_a[(t + 256) * 8]);
        GLL16(gb0 + k0, &lds_b[t * 8]);
        GLL16(gb1 + k0, &lds_b[(t + 256) * 8]);
        __syncthreads();   // compiler emits vmcnt(0) drain before barrier

        bf16x8 af[4], bfr[4];
#pragma unroll
        for (int m = 0; m < 4; ++m)
            af[m] = *(const bf16x8*)(pa + m * 16 * BK);
#pragma unroll
        for (int n = 0; n < 4; ++n)
            bfr[n] = *(const bf16x8*)(pb + n * 16 * BK);
#pragma unroll
        for (int m = 0; m < 4; ++m)
#pragma unroll
            for (int n = 0; n < 4; ++n)
                acc[m][n] = __builtin_amdgcn_mfma_f32_16x16x32_bf16(
                    af[m], bfr[n], acc[m][n], 0, 0, 0);
    }

    // epilogue: D[row=(lane>>4)*4+j, col=lane&15] per 16x16 fragment
    const int r0 = by * BM + wr * 64 + (lane >> 4) * 4;
    const int c0 = bx * BN + wc * 64 + fr;
#pragma unroll
    for (int n = 0; n < 4; ++n) {
        const int col = c0 + n * 16;
        const float sc = scale[col];
        const float bi = bias[col];
#pragma unroll
        for (int m = 0; m < 4; ++m) {
            const int row = r0 + m * 16;
#pragma unroll
            for (int j = 0; j < 4; ++j)
                C[(size_t)(row + j) * N + col] = acc[m][n][j] * sc + bi;
        }
    }
}

// ---------------- launch ----------------

extern "C" void kernel_launch(void* const* d_in, const int* in_sizes, int n_in,
                              void* d_out, int out_size, void* d_ws, size_t ws_size,
                              hipStream_t stream)
{
    const float* x    = (const float*)d_in[0];
    const float* wgt  = (const float*)d_in[1];
    const float* bias = (const float*)d_in[2];

    const int OUT = in_sizes[2];
    const int IN  = (int)((long long)in_sizes[1] / OUT);
    const int M   = (int)((long long)in_sizes[0] / IN);
    const int N = OUT, K = IN;

    double ad = (double)OUT / 10000.0;
    if (ad < 0.5) ad = 0.5;
    if (ad > 2.0) ad = 2.0;
    const double sfd = 60.0 * ad;      // = 30.0 for OUT=4096

    bf16_t* Q  = (bf16_t*)d_ws;
    bf16_t* Xb = (bf16_t*)((char*)d_ws + (size_t)OUT * IN * sizeof(bf16_t));
    float*  sc = (float*)((char*)d_ws + (size_t)OUT * IN * sizeof(bf16_t)
                                      + (size_t)M * IN * sizeof(bf16_t));
    float*  C  = (float*)d_out;

    quant_kernel<<<OUT, 256, 0, stream>>>(wgt, Q, sc, IN, sfd);

    long long n8 = (long long)M * IN / 8;
    int cblocks = (int)((n8 + 255) / 256);
    if (cblocks > 2048) cblocks = 2048;
    cvt_kernel<<<cblocks, 256, 0, stream>>>(x, Xb, n8);

    dim3 grid(N / BN, M / BM);
    gemm_kernel<<<grid, 256, 0, stream>>>(Xb, Q, sc, bias, C, M, N, K);
}

// Round 2
// 177.888 us; speedup vs baseline: 1.4081x; 1.4081x over previous
//
#include <hip/hip_runtime.h>
#include <hip/hip_bf16.h>

typedef __bf16 bf16_t;
typedef __bf16 bf16x8 __attribute__((ext_vector_type(8)));
typedef float f32x4 __attribute__((ext_vector_type(4)));

// async global->LDS, 16B per lane, dest = wave-uniform base + lane*16
#define GLL16(gp, lp)                                                          \
    __builtin_amdgcn_global_load_lds(                                          \
        (const __attribute__((address_space(1))) void*)(gp),                   \
        (__attribute__((address_space(3))) void*)(lp), 16, 0, 0)

#define SBAR() __builtin_amdgcn_s_barrier()
#define WAIT_VM4() asm volatile("s_waitcnt vmcnt(4)" ::: "memory")
#define WAIT_VM0() asm volatile("s_waitcnt vmcnt(0)" ::: "memory")
#define PH_SYNC()                                                              \
    do {                                                                       \
        __builtin_amdgcn_s_barrier();                                          \
        asm volatile("s_waitcnt lgkmcnt(0)" ::: "memory");                     \
        __builtin_amdgcn_sched_barrier(0);                                     \
    } while (0)
#define PH_END()                                                               \
    do {                                                                       \
        __builtin_amdgcn_s_setprio(0);                                         \
        __builtin_amdgcn_s_barrier();                                          \
    } while (0)
#define MFMA_(d, a, b)                                                         \
    d = __builtin_amdgcn_mfma_f32_16x16x32_bf16(a, b, d, 0, 0, 0)

// ---------------- E8 lattice quantization (fp64 decisions) ----------------

__device__ __forceinline__ void nearest_D8_d(const double x[8], double f[8]) {
    double d[8];
    double fs = 0.0;
#pragma unroll
    for (int i = 0; i < 8; ++i) {
        f[i] = rint(x[i]);              // round-half-to-even == jnp.round
        d[i] = x[i] - f[i];
        fs += f[i];
    }
    long long s = (long long)fs;
    if (s & 1LL) {
        int idx = 0;
        double best = fabs(d[0]);
#pragma unroll
        for (int i = 1; i < 8; ++i) {
            double a = fabs(d[i]);
            if (a > best) { best = a; idx = i; }   // strict > : first max
        }
        f[idx] += (d[idx] >= 0.0) ? 1.0 : -1.0;
    }
}

__device__ __forceinline__ void e8_quantize_d(const double x[8], float q[8]) {
    double y0[8], y1[8], xs[8];
    nearest_D8_d(x, y0);
#pragma unroll
    for (int i = 0; i < 8; ++i) xs[i] = x[i] - 0.5;
    nearest_D8_d(xs, y1);
#pragma unroll
    for (int i = 0; i < 8; ++i) y1[i] += 0.5;
    double d0 = 0.0, d1 = 0.0;
#pragma unroll
    for (int i = 0; i < 8; ++i) {
        double a = x[i] - y0[i]; d0 += a * a;
        double b = x[i] - y1[i]; d1 += b * b;
    }
    bool take0 = (d0 <= d1);
#pragma unroll
    for (int i = 0; i < 8; ++i) q[i] = (float)(take0 ? y0[i] : y1[i]);
}

__global__ __launch_bounds__(256) void quant_kernel(
    const float* __restrict__ W, bf16_t* __restrict__ Q,
    float* __restrict__ scale, int IN, double sfd)
{
    const int row  = blockIdx.x;
    const int t    = threadIdx.x;
    const int lane = t & 63, w = t >> 6;
    const float* wrow = W + (size_t)row * IN;

    double ss = 0.0;
    for (int i = t; i < (IN >> 2); i += 256) {
        float4 v = *(const float4*)(wrow + i * 4);
        double a = v.x, b = v.y, c = v.z, d = v.w;
        ss += a * a + b * b + c * c + d * d;
    }
#pragma unroll
    for (int m = 1; m < 64; m <<= 1) ss += __shfl_xor(ss, m);
    __shared__ double red[4];
    if (lane == 0) red[w] = ss;
    __syncthreads();
    double S   = (red[0] + red[1]) + (red[2] + red[3]);
    double nsd = fmax(sqrt(S), 1e-8);

    for (int b = t; b < (IN >> 3); b += 256) {
        const float* xp = wrow + b * 8;
        float4 v0 = *(const float4*)xp;
        float4 v1 = *(const float4*)(xp + 4);
        double xd[8] = {v0.x, v0.y, v0.z, v0.w, v1.x, v1.y, v1.z, v1.w};
        double xsd[8];
#pragma unroll
        for (int i = 0; i < 8; ++i) xsd[i] = (xd[i] / nsd) * sfd;
        float qf[8];
        e8_quantize_d(xsd, qf);
        bf16x8 o;
#pragma unroll
        for (int i = 0; i < 8; ++i) o[i] = (bf16_t)qf[i];
        *(bf16x8*)(Q + (size_t)row * IN + b * 8) = o;
    }
    if (t == 0) scale[row] = (float)(nsd / sfd);
}

// ---------------- x: f32 -> bf16, vectorized ----------------

__global__ void cvt_kernel(const float* __restrict__ x, bf16_t* __restrict__ y,
                           long long n8)
{
    long long i = (long long)blockIdx.x * blockDim.x + threadIdx.x;
    long long stride = (long long)gridDim.x * blockDim.x;
    for (; i < n8; i += stride) {
        float4 v0 = *(const float4*)(x + i * 8);
        float4 v1 = *(const float4*)(x + i * 8 + 4);
        bf16x8 o;
        o[0] = (bf16_t)v0.x; o[1] = (bf16_t)v0.y;
        o[2] = (bf16_t)v0.z; o[3] = (bf16_t)v0.w;
        o[4] = (bf16_t)v1.x; o[5] = (bf16_t)v1.y;
        o[6] = (bf16_t)v1.z; o[7] = (bf16_t)v1.w;
        *(bf16x8*)(y + i * 8) = o;
    }
}

// ---------------- GEMM: 256x256 tile, BK=64, 8 waves, 8-phase schedule
// C[m,n] = (sum_k A[m,k]*B[n,k]) * scale[n] + bias[n]
// LDS XOR-swizzle both-sides: pre-swizzled global source (linear GLL dest)
// + XOR'd ds_read address. Counted vmcnt(4), one per K-tile.

#define BM 256
#define BN 256
#define BK 64

__global__ __launch_bounds__(512, 2) void gemm_kernel(
    const bf16_t* __restrict__ A,      // [M][K]
    const bf16_t* __restrict__ B,      // [N][K]
    const float* __restrict__ scale,   // [N]
    const float* __restrict__ bias,    // [N]
    float* __restrict__ C,             // [M][N]
    int M, int N, int K)
{
    // [buf][A=0/B=1][half][128 rows * 64 cols]  = 128 KiB
    __shared__ __align__(16) bf16_t lds[2][2][2][8192];

    const int t    = threadIdx.x;
    const int lane = t & 63;
    const int w    = t >> 6;          // 0..7
    const int wr   = w >> 2;          // 0..1  (M rows of waves)
    const int wc   = w & 3;           // 0..3  (N cols of waves)

    // XCD-aware bijective block swizzle (m204)
    const int nwg = gridDim.x;
    const int bid = blockIdx.x;
    const int q8 = nwg >> 3, r8 = nwg & 7;
    const int xcd = bid & 7, idx = bid >> 3;
    const int swz = (xcd < r8 ? xcd * (q8 + 1) : r8 * (q8 + 1) + (xcd - r8) * q8) + idx;
    const int nbx = N / BN;
    const int bx = swz % nbx, by = swz / nbx;

    // staging source addressing (pre-swizzled k-slot so LDS dest is linear)
    const int rowq  = t >> 3;                          // 0..63
    const int kslot = ((t & 7) ^ (rowq & 7)) << 3;     // xor'd 8-elem slot
    const bf16_t* gA = A + (size_t)(by * BM + rowq) * K + kslot;
    const bf16_t* gB = B + (size_t)(bx * BN + rowq) * K + kslot;

#define STAGE(isB, bufi, h, kt)                                                \
    do {                                                                       \
        const bf16_t* s_ = ((isB) ? gB : gA)                                   \
            + (size_t)(h) * 128 * (size_t)K + (size_t)(kt) * BK;               \
        GLL16(s_,                   &lds[bufi][isB][h][t * 8]);                \
        GLL16(s_ + 64 * (size_t)K,  &lds[bufi][isB][h][t * 8 + 4096]);         \
    } while (0)

    // ds_read addressing: frag row r = R*16 + (lane&15); k-slot (s*4+lane>>4)
    // XOR'd with (r&7) == (lane&7). aoff folds (lane&15)*64 + swizzled slot*8.
    const int l15  = lane & 15;
    const int koff = lane >> 4;                        // 0..3
    const int aoff0 = l15 * 64 + (((koff)     ^ (lane & 7)) << 3);
    const int aoff1 = l15 * 64 + (((4 + koff) ^ (lane & 7)) << 3);

    f32x4 acc[8][4];
    const f32x4 zero = {0.f, 0.f, 0.f, 0.f};
#pragma unroll
    for (int R = 0; R < 8; ++R)
#pragma unroll
        for (int Cf = 0; Cf < 4; ++Cf) acc[R][Cf] = zero;

    const int NT = K / BK;

    // prologue: tile0 all 4 halves, tile1 A halves; vmcnt(4) leaves tile1 A
    STAGE(0, 0, 0, 0); STAGE(0, 0, 1, 0);
    STAGE(1, 0, 0, 0); STAGE(1, 0, 1, 0);
    STAGE(0, 1, 0, 1); STAGE(0, 1, 1, 1);
    WAIT_VM4();
    SBAR();

    bf16x8 af[4][2], b01[2][2], b23[2][2];

    for (int kt = 0; kt < NT; ++kt) {
        const int cur = kt & 1;
        const bf16_t* ldsA = &lds[cur][0][wr][0];
        const bf16_t* ldsB = &lds[cur][1][wc >> 1][(wc & 1) * 4096];
        const bool sb = (kt + 1 < NT);
        const bool sa = (kt + 2 < NT);

        // ---- phase 1: A r0-3 + B c0-1 reads; stage B-half0 of kt+1 ----
#pragma unroll
        for (int R = 0; R < 4; ++R) {
            af[R][0] = *(const bf16x8*)(ldsA + R * 1024 + aoff0);
            af[R][1] = *(const bf16x8*)(ldsA + R * 1024 + aoff1);
        }
#pragma unroll
        for (int c = 0; c < 2; ++c) {
            b01[c][0] = *(const bf16x8*)(ldsB + c * 1024 + aoff0);
            b01[c][1] = *(const bf16x8*)(ldsB + c * 1024 + aoff1);
        }
        if (sb) STAGE(1, cur ^ 1, 0, kt + 1);
        PH_SYNC();
        __builtin_amdgcn_s_setprio(1);
#pragma unroll
        for (int R = 0; R < 4; ++R)
#pragma unroll
            for (int s = 0; s < 2; ++s) {
                MFMA_(acc[R][0], af[R][s], b01[0][s]);
                MFMA_(acc[R][1], af[R][s], b01[1][s]);
            }
        PH_END();

        // ---- phase 2: B c2-3 reads; stage B-half1 of kt+1 ----
#pragma unroll
        for (int c = 0; c < 2; ++c) {
            b23[c][0] = *(const bf16x8*)(ldsB + (2 + c) * 1024 + aoff0);
            b23[c][1] = *(const bf16x8*)(ldsB + (2 + c) * 1024 + aoff1);
        }
        if (sb) STAGE(1, cur ^ 1, 1, kt + 1);
        PH_SYNC();
        __builtin_amdgcn_s_setprio(1);
#pragma unroll
        for (int R = 0; R < 4; ++R)
#pragma unroll
            for (int s = 0; s < 2; ++s) {
                MFMA_(acc[R][2], af[R][s], b23[0][s]);
                MFMA_(acc[R][3], af[R][s], b23[1][s]);
            }
        PH_END();

        // ---- phase 3: A r4-7 reads (reuse af regs); no stage ----
#pragma unroll
        for (int R = 0; R < 4; ++R) {
            af[R][0] = *(const bf16x8*)(ldsA + (4 + R) * 1024 + aoff0);
            af[R][1] = *(const bf16x8*)(ldsA + (4 + R) * 1024 + aoff1);
        }
        PH_SYNC();
        __builtin_amdgcn_s_setprio(1);
#pragma unroll
        for (int R = 0; R < 4; ++R)
#pragma unroll
            for (int s = 0; s < 2; ++s) {
                MFMA_(acc[4 + R][2], af[R][s], b23[0][s]);
                MFMA_(acc[4 + R][3], af[R][s], b23[1][s]);
            }
        PH_END();

        // ---- phase 4: B c0-1 re-read; stage A halves of kt+2; vmcnt ----
#pragma unroll
        for (int c = 0; c < 2; ++c) {
            b01[c][0] = *(const bf16x8*)(ldsB + c * 1024 + aoff0);
            b01[c][1] = *(const bf16x8*)(ldsB + c * 1024 + aoff1);
        }
        if (sa) { STAGE(0, cur, 0, kt + 2); STAGE(0, cur, 1, kt + 2); }
        if (kt < NT - 2) { WAIT_VM4(); }
        else if (kt == NT - 2) { WAIT_VM0(); }
        PH_SYNC();
        __builtin_amdgcn_s_setprio(1);
#pragma unroll
        for (int R = 0; R < 4; ++R)
#pragma unroll
            for (int s = 0; s < 2; ++s) {
                MFMA_(acc[4 + R][0], af[R][s], b01[0][s]);
                MFMA_(acc[4 + R][1], af[R][s], b01[1][s]);
            }
        PH_END();
    }

    // epilogue: D[row=(lane>>4)*4+j, col=lane&15] per 16x16 fragment
    const int r0 = by * BM + wr * 128 + (lane >> 4) * 4;
    const int c0 = bx * BN + wc * 64 + l15;
#pragma unroll
    for (int Cf = 0; Cf < 4; ++Cf) {
        const int col = c0 + Cf * 16;
        const float sc = scale[col];
        const float bi = bias[col];
#pragma unroll
        for (int R = 0; R < 8; ++R) {
            const int row = r0 + R * 16;
#pragma unroll
            for (int j = 0; j < 4; ++j)
                C[(size_t)(row + j) * N + col] = acc[R][Cf][j] * sc + bi;
        }
    }
#undef STAGE
}

// ---------------- launch ----------------

extern "C" void kernel_launch(void* const* d_in, const int* in_sizes, int n_in,
                              void* d_out, int out_size, void* d_ws, size_t ws_size,
                              hipStream_t stream)
{
    const float* x    = (const float*)d_in[0];
    const float* wgt  = (const float*)d_in[1];
    const float* bias = (const float*)d_in[2];

    const int OUT = in_sizes[2];
    const int IN  = (int)((long long)in_sizes[1] / OUT);
    const int M   = (int)((long long)in_sizes[0] / IN);
    const int N = OUT, K = IN;

    double ad = (double)OUT / 10000.0;
    if (ad < 0.5) ad = 0.5;
    if (ad > 2.0) ad = 2.0;
    const double sfd = 60.0 * ad;      // = 30.0 for OUT=4096

    bf16_t* Q  = (bf16_t*)d_ws;
    bf16_t* Xb = (bf16_t*)((char*)d_ws + (size_t)OUT * IN * sizeof(bf16_t));
    float*  sc = (float*)((char*)d_ws + (size_t)OUT * IN * sizeof(bf16_t)
                                      + (size_t)M * IN * sizeof(bf16_t));
    float*  C  = (float*)d_out;

    quant_kernel<<<OUT, 256, 0, stream>>>(wgt, Q, sc, IN, sfd);

    long long n8 = (long long)M * IN / 8;
    int cblocks = (int)((n8 + 255) / 256);
    if (cblocks > 2048) cblocks = 2048;
    cvt_kernel<<<cblocks, 256, 0, stream>>>(x, Xb, n8);

    int grid = (M / BM) * (N / BN);
    gemm_kernel<<<grid, 512, 0, stream>>>(Xb, Q, sc, bias, C, M, N, K);
}

// Round 3
// 171.114 us; speedup vs baseline: 1.4639x; 1.0396x over previous
//
#include <hip/hip_runtime.h>
#include <hip/hip_bf16.h>

typedef __bf16 bf16_t;
typedef __bf16 bf16x8 __attribute__((ext_vector_type(8)));
typedef float f32x4 __attribute__((ext_vector_type(4)));

// async global->LDS, 16B per lane, dest = wave-uniform base + lane*16
#define GLL16(gp, lp)                                                          \
    __builtin_amdgcn_global_load_lds(                                          \
        (const __attribute__((address_space(1))) void*)(gp),                   \
        (__attribute__((address_space(3))) void*)(lp), 16, 0, 0)

#define SBAR() __builtin_amdgcn_s_barrier()
#define WAIT_VM8() asm volatile("s_waitcnt vmcnt(8)" ::: "memory")
#define WAIT_VM0() asm volatile("s_waitcnt vmcnt(0)" ::: "memory")
#define PH_SYNC()                                                              \
    do {                                                                       \
        __builtin_amdgcn_s_barrier();                                          \
        asm volatile("s_waitcnt lgkmcnt(0)" ::: "memory");                     \
        __builtin_amdgcn_sched_barrier(0);                                     \
    } while (0)
#define PH_END()                                                               \
    do {                                                                       \
        __builtin_amdgcn_s_setprio(0);                                         \
        __builtin_amdgcn_s_barrier();                                          \
    } while (0)
#define MFMA_(d, a, b)                                                         \
    d = __builtin_amdgcn_mfma_f32_16x16x32_bf16(a, b, d, 0, 0, 0)

// ---------------- E8 lattice quantization (fp64 decisions) ----------------

__device__ __forceinline__ void nearest_D8_d(const double x[8], double f[8]) {
    double d[8];
    double fs = 0.0;
#pragma unroll
    for (int i = 0; i < 8; ++i) {
        f[i] = rint(x[i]);              // round-half-to-even == jnp.round
        d[i] = x[i] - f[i];
        fs += f[i];
    }
    long long s = (long long)fs;
    if (s & 1LL) {
        int idx = 0;
        double best = fabs(d[0]);
#pragma unroll
        for (int i = 1; i < 8; ++i) {
            double a = fabs(d[i]);
            if (a > best) { best = a; idx = i; }   // strict > : first max
        }
        f[idx] += (d[idx] >= 0.0) ? 1.0 : -1.0;
    }
}

__device__ __forceinline__ void e8_quantize_d(const double x[8], float q[8]) {
    double y0[8], y1[8], xs[8];
    nearest_D8_d(x, y0);
#pragma unroll
    for (int i = 0; i < 8; ++i) xs[i] = x[i] - 0.5;
    nearest_D8_d(xs, y1);
#pragma unroll
    for (int i = 0; i < 8; ++i) y1[i] += 0.5;
    double d0 = 0.0, d1 = 0.0;
#pragma unroll
    for (int i = 0; i < 8; ++i) {
        double a = x[i] - y0[i]; d0 += a * a;
        double b = x[i] - y1[i]; d1 += b * b;
    }
    bool take0 = (d0 <= d1);
#pragma unroll
    for (int i = 0; i < 8; ++i) q[i] = (float)(take0 ? y0[i] : y1[i]);
}

// fused: blocks [0,OUT) quantize weight rows; blocks [OUT, OUT+CB) cvt x->bf16
__global__ __launch_bounds__(256) void prep_kernel(
    const float* __restrict__ W, bf16_t* __restrict__ Q,
    float* __restrict__ scale, int IN, double sfd,
    const float* __restrict__ x, bf16_t* __restrict__ Xb, long long n8,
    int OUT, int CB)
{
    if (blockIdx.x >= (unsigned)OUT) {
        // ---- cvt part ----
        long long i = (long long)(blockIdx.x - OUT) * 256 + threadIdx.x;
        long long stride = (long long)CB * 256;
        for (; i < n8; i += stride) {
            float4 v0 = *(const float4*)(x + i * 8);
            float4 v1 = *(const float4*)(x + i * 8 + 4);
            bf16x8 o;
            o[0] = (bf16_t)v0.x; o[1] = (bf16_t)v0.y;
            o[2] = (bf16_t)v0.z; o[3] = (bf16_t)v0.w;
            o[4] = (bf16_t)v1.x; o[5] = (bf16_t)v1.y;
            o[6] = (bf16_t)v1.z; o[7] = (bf16_t)v1.w;
            *(bf16x8*)(Xb + i * 8) = o;
        }
        return;
    }
    // ---- quant part ----
    const int row  = blockIdx.x;
    const int t    = threadIdx.x;
    const int lane = t & 63, w = t >> 6;
    const float* wrow = W + (size_t)row * IN;

    double ss = 0.0;
    for (int i = t; i < (IN >> 2); i += 256) {
        float4 v = *(const float4*)(wrow + i * 4);
        double a = v.x, b = v.y, c = v.z, d = v.w;
        ss += a * a + b * b + c * c + d * d;
    }
#pragma unroll
    for (int m = 1; m < 64; m <<= 1) ss += __shfl_xor(ss, m);
    __shared__ double red[4];
    if (lane == 0) red[w] = ss;
    __syncthreads();
    double S   = (red[0] + red[1]) + (red[2] + red[3]);
    double nsd = fmax(sqrt(S), 1e-8);

    for (int b = t; b < (IN >> 3); b += 256) {
        const float* xp = wrow + b * 8;
        float4 v0 = *(const float4*)xp;
        float4 v1 = *(const float4*)(xp + 4);
        double xd[8] = {v0.x, v0.y, v0.z, v0.w, v1.x, v1.y, v1.z, v1.w};
        double xsd[8];
#pragma unroll
        for (int i = 0; i < 8; ++i) xsd[i] = (xd[i] / nsd) * sfd;
        float qf[8];
        e8_quantize_d(xsd, qf);
        bf16x8 o;
#pragma unroll
        for (int i = 0; i < 8; ++i) o[i] = (bf16_t)qf[i];
        *(bf16x8*)(Q + (size_t)row * IN + b * 8) = o;
    }
    if (t == 0) scale[row] = (float)(nsd / sfd);
}

// ---------------- GEMM: 256x256 tile, BK=64, 8 waves, 4-phase/K-tile
// Deep prefetch: during tile kt, stage tile kt+2 (B at P3, A at P4);
// per-tile vmcnt(8) drains tile kt+1's 8 loads issued a FULL tile earlier.
// C[m,n] = (sum_k A[m,k]*B[n,k]) * scale[n] + bias[n]

#define BM 256
#define BN 256
#define BK 64

__global__ __launch_bounds__(512, 2) void gemm_kernel(
    const bf16_t* __restrict__ A,      // [M][K]
    const bf16_t* __restrict__ B,      // [N][K]
    const float* __restrict__ scale,   // [N]
    const float* __restrict__ bias,    // [N]
    float* __restrict__ C,             // [M][N]
    int M, int N, int K)
{
    // [buf][A=0/B=1][half][128 rows * 64 cols]  = 128 KiB
    __shared__ __align__(16) bf16_t lds[2][2][2][8192];

    const int t    = threadIdx.x;
    const int lane = t & 63;
    const int w    = t >> 6;          // 0..7
    const int wr   = w >> 2;          // 0..1  (M rows of waves)
    const int wc   = w & 3;           // 0..3  (N cols of waves)

    // XCD-aware bijective block swizzle (m204)
    const int nwg = gridDim.x;
    const int bid = blockIdx.x;
    const int q8 = nwg >> 3, r8 = nwg & 7;
    const int xcd = bid & 7, idx = bid >> 3;
    const int swz = (xcd < r8 ? xcd * (q8 + 1) : r8 * (q8 + 1) + (xcd - r8) * q8) + idx;
    const int nbx = N / BN;
    const int bx = swz % nbx, by = swz / nbx;

    // staging source addressing (pre-swizzled k-slot so LDS dest is linear)
    const int rowq  = t >> 3;                          // 0..63
    const int kslot = ((t & 7) ^ (rowq & 7)) << 3;     // xor'd 8-elem slot
    const bf16_t* gA = A + (size_t)(by * BM + rowq) * K + kslot;
    const bf16_t* gB = B + (size_t)(bx * BN + rowq) * K + kslot;

#define STAGE(isB, bufi, h, kt)                                                \
    do {                                                                       \
        const bf16_t* s_ = ((isB) ? gB : gA)                                   \
            + (size_t)(h) * 128 * (size_t)K + (size_t)(kt) * BK;               \
        GLL16(s_,                   &lds[bufi][isB][h][t * 8]);                \
        GLL16(s_ + 64 * (size_t)K,  &lds[bufi][isB][h][t * 8 + 4096]);         \
    } while (0)

    // ds_read addressing: frag row r = R*16 + (lane&15); k-slot (s*4+lane>>4)
    // XOR'd with (r&7) == (lane&7). aoff folds (lane&15)*64 + swizzled slot*8.
    const int l15  = lane & 15;
    const int koff = lane >> 4;                        // 0..3
    const int aoff0 = l15 * 64 + (((koff)     ^ (lane & 7)) << 3);
    const int aoff1 = l15 * 64 + (((4 + koff) ^ (lane & 7)) << 3);

    f32x4 acc[8][4];
    const f32x4 zero = {0.f, 0.f, 0.f, 0.f};
#pragma unroll
    for (int R = 0; R < 8; ++R)
#pragma unroll
        for (int Cf = 0; Cf < 4; ++Cf) acc[R][Cf] = zero;

    const int NT = K / BK;

    // prologue: tile0 (8 ops) then tile1 (8 ops); vmcnt(8) -> tile0 ready
    STAGE(1, 0, 0, 0); STAGE(1, 0, 1, 0);
    STAGE(0, 0, 0, 0); STAGE(0, 0, 1, 0);
    if (NT > 1) {
        STAGE(1, 1, 0, 1); STAGE(1, 1, 1, 1);
        STAGE(0, 1, 0, 1); STAGE(0, 1, 1, 1);
        WAIT_VM8();
    } else {
        WAIT_VM0();
    }
    SBAR();

    bf16x8 af[4][2], b01[2][2], b23[2][2];

    for (int kt = 0; kt < NT; ++kt) {
        const int cur = kt & 1;
        const bf16_t* ldsA = &lds[cur][0][wr][0];
        const bf16_t* ldsB = &lds[cur][1][wc >> 1][(wc & 1) * 4096];
        const bool s2 = (kt + 2 < NT);

        // ---- P1: read A r0-3 + B c0-1 (12 ds_reads); MFMA Q1 ----
#pragma unroll
        for (int R = 0; R < 4; ++R) {
            af[R][0] = *(const bf16x8*)(ldsA + R * 1024 + aoff0);
            af[R][1] = *(const bf16x8*)(ldsA + R * 1024 + aoff1);
        }
#pragma unroll
        for (int c = 0; c < 2; ++c) {
            b01[c][0] = *(const bf16x8*)(ldsB + c * 1024 + aoff0);
            b01[c][1] = *(const bf16x8*)(ldsB + c * 1024 + aoff1);
        }
        asm volatile("s_waitcnt lgkmcnt(8)" ::: "memory");
        PH_SYNC();
        __builtin_amdgcn_s_setprio(1);
#pragma unroll
        for (int s = 0; s < 2; ++s)
#pragma unroll
            for (int R = 0; R < 4; ++R) {
                MFMA_(acc[R][0], af[R][s], b01[0][s]);
                MFMA_(acc[R][1], af[R][s], b01[1][s]);
            }
        PH_END();

        // ---- P2: read B c2-3 (4 ds_reads); MFMA Q2 ----
#pragma unroll
        for (int c = 0; c < 2; ++c) {
            b23[c][0] = *(const bf16x8*)(ldsB + (2 + c) * 1024 + aoff0);
            b23[c][1] = *(const bf16x8*)(ldsB + (2 + c) * 1024 + aoff1);
        }
        PH_SYNC();
        __builtin_amdgcn_s_setprio(1);
#pragma unroll
        for (int s = 0; s < 2; ++s)
#pragma unroll
            for (int R = 0; R < 4; ++R) {
                MFMA_(acc[R][2], af[R][s], b23[0][s]);
                MFMA_(acc[R][3], af[R][s], b23[1][s]);
            }
        PH_END();

        // ---- P3: read A r4-7 (8 ds_reads); stage B(kt+2); MFMA Q3 ----
#pragma unroll
        for (int R = 0; R < 4; ++R) {
            af[R][0] = *(const bf16x8*)(ldsA + (4 + R) * 1024 + aoff0);
            af[R][1] = *(const bf16x8*)(ldsA + (4 + R) * 1024 + aoff1);
        }
        if (s2) { STAGE(1, cur, 0, kt + 2); STAGE(1, cur, 1, kt + 2); }
        PH_SYNC();
        __builtin_amdgcn_s_setprio(1);
#pragma unroll
        for (int s = 0; s < 2; ++s)
#pragma unroll
            for (int R = 0; R < 4; ++R) {
                MFMA_(acc[4 + R][2], af[R][s], b23[0][s]);
                MFMA_(acc[4 + R][3], af[R][s], b23[1][s]);
            }
        PH_END();

        // ---- P4: no reads; stage A(kt+2); MFMA Q4 (b01 kept live); wait ----
        if (s2) { STAGE(0, cur, 0, kt + 2); STAGE(0, cur, 1, kt + 2); }
        PH_SYNC();
        __builtin_amdgcn_s_setprio(1);
#pragma unroll
        for (int s = 0; s < 2; ++s)
#pragma unroll
            for (int R = 0; R < 4; ++R) {
                MFMA_(acc[4 + R][0], af[R][s], b01[0][s]);
                MFMA_(acc[4 + R][1], af[R][s], b01[1][s]);
            }
        if (kt < NT - 2) { WAIT_VM8(); }
        else if (kt == NT - 2) { WAIT_VM0(); }
        PH_END();
    }

    // epilogue: D[row=(lane>>4)*4+j, col=lane&15] per 16x16 fragment
    const int r0 = by * BM + wr * 128 + (lane >> 4) * 4;
    const int c0 = bx * BN + wc * 64 + l15;
#pragma unroll
    for (int Cf = 0; Cf < 4; ++Cf) {
        const int col = c0 + Cf * 16;
        const float sc = scale[col];
        const float bi = bias[col];
#pragma unroll
        for (int R = 0; R < 8; ++R) {
            const int row = r0 + R * 16;
#pragma unroll
            for (int j = 0; j < 4; ++j)
                C[(size_t)(row + j) * N + col] = acc[R][Cf][j] * sc + bi;
        }
    }
#undef STAGE
}

// ---------------- launch ----------------

extern "C" void kernel_launch(void* const* d_in, const int* in_sizes, int n_in,
                              void* d_out, int out_size, void* d_ws, size_t ws_size,
                              hipStream_t stream)
{
    const float* x    = (const float*)d_in[0];
    const float* wgt  = (const float*)d_in[1];
    const float* bias = (const float*)d_in[2];

    const int OUT = in_sizes[2];
    const int IN  = (int)((long long)in_sizes[1] / OUT);
    const int M   = (int)((long long)in_sizes[0] / IN);
    const int N = OUT, K = IN;

    double ad = (double)OUT / 10000.0;
    if (ad < 0.5) ad = 0.5;
    if (ad > 2.0) ad = 2.0;
    const double sfd = 60.0 * ad;      // = 30.0 for OUT=4096

    bf16_t* Q  = (bf16_t*)d_ws;
    bf16_t* Xb = (bf16_t*)((char*)d_ws + (size_t)OUT * IN * sizeof(bf16_t));
    float*  sc = (float*)((char*)d_ws + (size_t)OUT * IN * sizeof(bf16_t)
                                      + (size_t)M * IN * sizeof(bf16_t));
    float*  C  = (float*)d_out;

    long long n8 = (long long)M * IN / 8;
    const int CB = 2048;
    prep_kernel<<<OUT + CB, 256, 0, stream>>>(wgt, Q, sc, IN, sfd,
                                              x, Xb, n8, OUT, CB);

    int grid = (M / BM) * (N / BN);
    gemm_kernel<<<grid, 512, 0, stream>>>(Xb, Q, sc, bias, C, M, N, K);
}

// Round 4
// 157.773 us; speedup vs baseline: 1.5877x; 1.0846x over previous
//
#include <hip/hip_runtime.h>
#include <hip/hip_bf16.h>

typedef __bf16 bf16_t;
typedef __bf16 bf16x8 __attribute__((ext_vector_type(8)));
typedef float f32x4 __attribute__((ext_vector_type(4)));

// async global->LDS, 16B per lane, dest = wave-uniform base + lane*16
#define GLL16(gp, lp)                                                          \
    __builtin_amdgcn_global_load_lds(                                          \
        (const __attribute__((address_space(1))) void*)(gp),                   \
        (__attribute__((address_space(3))) void*)(lp), 16, 0, 0)

#define SBAR() __builtin_amdgcn_s_barrier()
#define SCHED0() __builtin_amdgcn_sched_barrier(0)
#define WAIT_VM8() asm volatile("s_waitcnt vmcnt(8)" ::: "memory")
#define WAIT_VM0() asm volatile("s_waitcnt vmcnt(0)" ::: "memory")
#define MFMA_(d, a, b)                                                         \
    d = __builtin_amdgcn_mfma_f32_16x16x32_bf16(a, b, d, 0, 0, 0)

// ---------------- E8 lattice quantization (fp64 decisions) ----------------

__device__ __forceinline__ void nearest_D8_d(const double x[8], double f[8]) {
    double d[8];
    double fs = 0.0;
#pragma unroll
    for (int i = 0; i < 8; ++i) {
        f[i] = rint(x[i]);              // round-half-to-even == jnp.round
        d[i] = x[i] - f[i];
        fs += f[i];
    }
    long long s = (long long)fs;
    if (s & 1LL) {
        int idx = 0;
        double best = fabs(d[0]);
#pragma unroll
        for (int i = 1; i < 8; ++i) {
            double a = fabs(d[i]);
            if (a > best) { best = a; idx = i; }   // strict > : first max
        }
        f[idx] += (d[idx] >= 0.0) ? 1.0 : -1.0;
    }
}

__device__ __forceinline__ void e8_quantize_d(const double x[8], float q[8]) {
    double y0[8], y1[8], xs[8];
    nearest_D8_d(x, y0);
#pragma unroll
    for (int i = 0; i < 8; ++i) xs[i] = x[i] - 0.5;
    nearest_D8_d(xs, y1);
#pragma unroll
    for (int i = 0; i < 8; ++i) y1[i] += 0.5;
    double d0 = 0.0, d1 = 0.0;
#pragma unroll
    for (int i = 0; i < 8; ++i) {
        double a = x[i] - y0[i]; d0 += a * a;
        double b = x[i] - y1[i]; d1 += b * b;
    }
    bool take0 = (d0 <= d1);
#pragma unroll
    for (int i = 0; i < 8; ++i) q[i] = (float)(take0 ? y0[i] : y1[i]);
}

// fused: blocks [0,OUT) quantize weight rows; blocks [OUT, OUT+CB) cvt x->bf16
__global__ __launch_bounds__(256) void prep_kernel(
    const float* __restrict__ W, bf16_t* __restrict__ Q,
    float* __restrict__ scale, int IN, double sfd,
    const float* __restrict__ x, bf16_t* __restrict__ Xb, long long n8,
    int OUT, int CB)
{
    if (blockIdx.x >= (unsigned)OUT) {
        // ---- cvt part ----
        long long i = (long long)(blockIdx.x - OUT) * 256 + threadIdx.x;
        long long stride = (long long)CB * 256;
        for (; i < n8; i += stride) {
            float4 v0 = *(const float4*)(x + i * 8);
            float4 v1 = *(const float4*)(x + i * 8 + 4);
            bf16x8 o;
            o[0] = (bf16_t)v0.x; o[1] = (bf16_t)v0.y;
            o[2] = (bf16_t)v0.z; o[3] = (bf16_t)v0.w;
            o[4] = (bf16_t)v1.x; o[5] = (bf16_t)v1.y;
            o[6] = (bf16_t)v1.z; o[7] = (bf16_t)v1.w;
            *(bf16x8*)(Xb + i * 8) = o;
        }
        return;
    }
    // ---- quant part ----
    const int row  = blockIdx.x;
    const int t    = threadIdx.x;
    const int lane = t & 63, w = t >> 6;
    const float* wrow = W + (size_t)row * IN;

    double ss = 0.0;
    for (int i = t; i < (IN >> 2); i += 256) {
        float4 v = *(const float4*)(wrow + i * 4);
        double a = v.x, b = v.y, c = v.z, d = v.w;
        ss += a * a + b * b + c * c + d * d;
    }
#pragma unroll
    for (int m = 1; m < 64; m <<= 1) ss += __shfl_xor(ss, m);
    __shared__ double red[4];
    if (lane == 0) red[w] = ss;
    __syncthreads();
    double S   = (red[0] + red[1]) + (red[2] + red[3]);
    double nsd = fmax(sqrt(S), 1e-8);

    for (int b = t; b < (IN >> 3); b += 256) {
        const float* xp = wrow + b * 8;
        float4 v0 = *(const float4*)xp;
        float4 v1 = *(const float4*)(xp + 4);
        double xd[8] = {v0.x, v0.y, v0.z, v0.w, v1.x, v1.y, v1.z, v1.w};
        double xsd[8];
#pragma unroll
        for (int i = 0; i < 8; ++i) xsd[i] = (xd[i] / nsd) * sfd;
        float qf[8];
        e8_quantize_d(xsd, qf);
        bf16x8 o;
#pragma unroll
        for (int i = 0; i < 8; ++i) o[i] = (bf16_t)qf[i];
        *(bf16x8*)(Q + (size_t)row * IN + b * 8) = o;
    }
    if (t == 0) scale[row] = (float)(nsd / sfd);
}

// ---------------- GEMM: 256x256 tile, BK=64, 8 waves.
// 3-barrier K-tile: reads/MFMA overlap across waves inside each window;
// barriers only where a restage or cross-tile handoff requires collectivity.
// C[m,n] = (sum_k A[m,k]*B[n,k]) * scale[n] + bias[n]

#define BM 256
#define BN 256
#define BK 64

__global__ __launch_bounds__(512, 2) void gemm_kernel(
    const bf16_t* __restrict__ A,      // [M][K]
    const bf16_t* __restrict__ B,      // [N][K]
    const float* __restrict__ scale,   // [N]
    const float* __restrict__ bias,    // [N]
    float* __restrict__ C,             // [M][N]
    int M, int N, int K)
{
    // [buf][A=0/B=1][half][128 rows * 64 cols]  = 128 KiB
    __shared__ __align__(16) bf16_t lds[2][2][2][8192];

    const int t    = threadIdx.x;
    const int lane = t & 63;
    const int w    = t >> 6;          // 0..7
    const int wr   = w >> 2;          // 0..1  (M rows of waves)
    const int wc   = w & 3;           // 0..3  (N cols of waves)

    // XCD-aware bijective block swizzle (m204)
    const int nwg = gridDim.x;
    const int bid = blockIdx.x;
    const int q8 = nwg >> 3, r8 = nwg & 7;
    const int xcd = bid & 7, idx = bid >> 3;
    const int swz = (xcd < r8 ? xcd * (q8 + 1) : r8 * (q8 + 1) + (xcd - r8) * q8) + idx;
    const int nbx = N / BN;
    const int bx = swz % nbx, by = swz / nbx;

    // staging source addressing (pre-swizzled k-slot so LDS dest is linear)
    const int rowq  = t >> 3;                          // 0..63
    const int kslot = ((t & 7) ^ (rowq & 7)) << 3;     // xor'd 8-elem slot
    const bf16_t* gA = A + (size_t)(by * BM + rowq) * K + kslot;
    const bf16_t* gB = B + (size_t)(bx * BN + rowq) * K + kslot;

#define STAGE(isB, bufi, h, kt)                                                \
    do {                                                                       \
        const bf16_t* s_ = ((isB) ? gB : gA)                                   \
            + (size_t)(h) * 128 * (size_t)K + (size_t)(kt) * BK;               \
        GLL16(s_,                   &lds[bufi][isB][h][t * 8]);                \
        GLL16(s_ + 64 * (size_t)K,  &lds[bufi][isB][h][t * 8 + 4096]);         \
    } while (0)

    // ds_read addressing: frag row r = R*16 + (lane&15); k-slot (s*4+lane>>4)
    // XOR'd with (r&7) == (lane&7). aoff folds (lane&15)*64 + swizzled slot*8.
    const int l15  = lane & 15;
    const int koff = lane >> 4;                        // 0..3
    const int aoff0 = l15 * 64 + (((koff)     ^ (lane & 7)) << 3);
    const int aoff1 = l15 * 64 + (((4 + koff) ^ (lane & 7)) << 3);

    f32x4 acc[8][4];
    const f32x4 zero = {0.f, 0.f, 0.f, 0.f};
#pragma unroll
    for (int R = 0; R < 8; ++R)
#pragma unroll
        for (int Cf = 0; Cf < 4; ++Cf) acc[R][Cf] = zero;

    const int NT = K / BK;

    // prologue: tile0 (8 ops) then tile1 (8 ops); vmcnt(8) -> tile0 ready
    STAGE(1, 0, 0, 0); STAGE(1, 0, 1, 0);
    STAGE(0, 0, 0, 0); STAGE(0, 0, 1, 0);
    if (NT > 1) {
        STAGE(1, 1, 0, 1); STAGE(1, 1, 1, 1);
        STAGE(0, 1, 0, 1); STAGE(0, 1, 1, 1);
        WAIT_VM8();
    } else {
        WAIT_VM0();
    }
    SBAR();
    SCHED0();

    bf16x8 af[4][2], b01[2][2], b23[2][2];

    for (int kt = 0; kt < NT; ++kt) {
        const int cur = kt & 1;
        const bf16_t* ldsA = &lds[cur][0][wr][0];
        const bf16_t* ldsB = &lds[cur][1][wc >> 1][(wc & 1) * 4096];
        const bool s2 = (kt + 2 < NT);

        // ==== W1: 16 ds_reads (A r0-3, B c0-3); MFMA Q1+Q2 ====
        // (compiler inserts fine-grained lgkmcnt and interleaves)
#pragma unroll
        for (int R = 0; R < 4; ++R) {
            af[R][0] = *(const bf16x8*)(ldsA + R * 1024 + aoff0);
            af[R][1] = *(const bf16x8*)(ldsA + R * 1024 + aoff1);
        }
#pragma unroll
        for (int c = 0; c < 2; ++c) {
            b01[c][0] = *(const bf16x8*)(ldsB + c * 1024 + aoff0);
            b01[c][1] = *(const bf16x8*)(ldsB + c * 1024 + aoff1);
        }
#pragma unroll
        for (int c = 0; c < 2; ++c) {
            b23[c][0] = *(const bf16x8*)(ldsB + (2 + c) * 1024 + aoff0);
            b23[c][1] = *(const bf16x8*)(ldsB + (2 + c) * 1024 + aoff1);
        }
        __builtin_amdgcn_s_setprio(1);
#pragma unroll
        for (int s = 0; s < 2; ++s)
#pragma unroll
            for (int R = 0; R < 4; ++R) {
                MFMA_(acc[R][0], af[R][s], b01[0][s]);
                MFMA_(acc[R][1], af[R][s], b01[1][s]);
            }
#pragma unroll
        for (int s = 0; s < 2; ++s)
#pragma unroll
            for (int R = 0; R < 4; ++R) {
                MFMA_(acc[R][2], af[R][s], b23[0][s]);
                MFMA_(acc[R][3], af[R][s], b23[1][s]);
            }
        __builtin_amdgcn_s_setprio(0);
        SBAR();            // all waves' B-reads of tile kt complete
        SCHED0();

        // ==== W2: 8 ds_reads (A r4-7); stage B(kt+2); MFMA Q3 ====
#pragma unroll
        for (int R = 0; R < 4; ++R) {
            af[R][0] = *(const bf16x8*)(ldsA + (4 + R) * 1024 + aoff0);
            af[R][1] = *(const bf16x8*)(ldsA + (4 + R) * 1024 + aoff1);
        }
        if (s2) { STAGE(1, cur, 0, kt + 2); STAGE(1, cur, 1, kt + 2); }
        __builtin_amdgcn_s_setprio(1);
#pragma unroll
        for (int s = 0; s < 2; ++s)
#pragma unroll
            for (int R = 0; R < 4; ++R) {
                MFMA_(acc[4 + R][2], af[R][s], b23[0][s]);
                MFMA_(acc[4 + R][3], af[R][s], b23[1][s]);
            }
        __builtin_amdgcn_s_setprio(0);
        SBAR();            // all waves' A-reads of tile kt complete
        SCHED0();

        // ==== W3: stage A(kt+2); MFMA Q4 (b01 kept live); vmcnt handoff ====
        if (s2) { STAGE(0, cur, 0, kt + 2); STAGE(0, cur, 1, kt + 2); }
        __builtin_amdgcn_s_setprio(1);
#pragma unroll
        for (int s = 0; s < 2; ++s)
#pragma unroll
            for (int R = 0; R < 4; ++R) {
                MFMA_(acc[4 + R][0], af[R][s], b01[0][s]);
                MFMA_(acc[4 + R][1], af[R][s], b01[1][s]);
            }
        __builtin_amdgcn_s_setprio(0);
        if (kt < NT - 2) { WAIT_VM8(); }
        else if (kt == NT - 2) { WAIT_VM0(); }
        SBAR();            // tile kt+1 resident for all waves
        SCHED0();
    }

    // epilogue: D[row=(lane>>4)*4+j, col=lane&15] per 16x16 fragment
    const int r0 = by * BM + wr * 128 + (lane >> 4) * 4;
    const int c0 = bx * BN + wc * 64 + l15;
#pragma unroll
    for (int Cf = 0; Cf < 4; ++Cf) {
        const int col = c0 + Cf * 16;
        const float sc = scale[col];
        const float bi = bias[col];
#pragma unroll
        for (int R = 0; R < 8; ++R) {
            const int row = r0 + R * 16;
#pragma unroll
            for (int j = 0; j < 4; ++j)
                C[(size_t)(row + j) * N + col] = acc[R][Cf][j] * sc + bi;
        }
    }
#undef STAGE
}

// ---------------- launch ----------------

extern "C" void kernel_launch(void* const* d_in, const int* in_sizes, int n_in,
                              void* d_out, int out_size, void* d_ws, size_t ws_size,
                              hipStream_t stream)
{
    const float* x    = (const float*)d_in[0];
    const float* wgt  = (const float*)d_in[1];
    const float* bias = (const float*)d_in[2];

    const int OUT = in_sizes[2];
    const int IN  = (int)((long long)in_sizes[1] / OUT);
    const int M   = (int)((long long)in_sizes[0] / IN);
    const int N = OUT, K = IN;

    double ad = (double)OUT / 10000.0;
    if (ad < 0.5) ad = 0.5;
    if (ad > 2.0) ad = 2.0;
    const double sfd = 60.0 * ad;      // = 30.0 for OUT=4096

    bf16_t* Q  = (bf16_t*)d_ws;
    bf16_t* Xb = (bf16_t*)((char*)d_ws + (size_t)OUT * IN * sizeof(bf16_t));
    float*  sc = (float*)((char*)d_ws + (size_t)OUT * IN * sizeof(bf16_t)
                                      + (size_t)M * IN * sizeof(bf16_t));
    float*  C  = (float*)d_out;

    long long n8 = (long long)M * IN / 8;
    const int CB = 2048;
    prep_kernel<<<OUT + CB, 256, 0, stream>>>(wgt, Q, sc, IN, sfd,
                                              x, Xb, n8, OUT, CB);

    int grid = (M / BM) * (N / BN);
    gemm_kernel<<<grid, 512, 0, stream>>>(Xb, Q, sc, bias, C, M, N, K);
}